// Round 6
// baseline (7131.714 us; speedup 1.0000x reference)
//
#include <hip/hip_runtime.h>
#include <hip/hip_bf16.h>

#define SS 4096
#define TT 2048
#define RP 4104   // padded LDS row pitch (ushorts): +8 kills row-stride bank aliasing

// clang native vector type: usable directly in asm "v" constraints
typedef float v4f __attribute__((ext_vector_type(4)));

// ---------- LLC-coherent (agent) memory ops, hand-rolled ----------
// sc0 sc1 => bypass non-coherent per-XCD L2, serve at Infinity Cache.

__device__ __forceinline__ void llc_load4x2(const v4f* p, v4f& a, v4f& b) {
  asm volatile(
      "global_load_dwordx4 %0, %2, off sc0 sc1\n\t"
      "global_load_dwordx4 %1, %3, off sc0 sc1\n\t"
      "s_waitcnt vmcnt(0)"
      : "=&v"(a), "=&v"(b)
      : "v"(p), "v"(p + 512)
      : "memory");
}

__device__ __forceinline__ void llc_store_drain(float* p, float v) {
  asm volatile("global_store_dword %0, %1, off sc0 sc1\n\t"
               "s_waitcnt vmcnt(0)"
               :: "v"(p), "v"(v) : "memory");
}

// ---------- helpers ----------

__device__ __forceinline__ unsigned short f2bf_rn(float f) {
  unsigned int u = __float_as_uint(f);
  u += 0x7FFFu + ((u >> 16) & 1u);   // RNE; inputs positive finite
  return (unsigned short)(u >> 16);
}

// OR of (sign-adjusted) words: ready iff top bit of result is 0
__device__ __forceinline__ unsigned orsgn(v4f v, unsigned e) {
  return (__float_as_uint(v.x) ^ e) | (__float_as_uint(v.y) ^ e)
       | (__float_as_uint(v.z) ^ e) | (__float_as_uint(v.w) ^ e);
}

__device__ __forceinline__ uint4 xorsgn(v4f v, unsigned e) {
  uint4 r;
  r.x = __float_as_uint(v.x) ^ e;  r.y = __float_as_uint(v.y) ^ e;
  r.z = __float_as_uint(v.z) ^ e;  r.w = __float_as_uint(v.w) ^ e;
  return r;
}

__device__ __forceinline__ float dot8(uint4 u, v4f qa, v4f qb, float acc) {
  acc = fmaf(__uint_as_float(u.x << 16),          qa.x, acc);
  acc = fmaf(__uint_as_float(u.x & 0xFFFF0000u),  qa.y, acc);
  acc = fmaf(__uint_as_float(u.y << 16),          qa.z, acc);
  acc = fmaf(__uint_as_float(u.y & 0xFFFF0000u),  qa.w, acc);
  acc = fmaf(__uint_as_float(u.z << 16),          qb.x, acc);
  acc = fmaf(__uint_as_float(u.z & 0xFFFF0000u),  qb.y, acc);
  acc = fmaf(__uint_as_float(u.w << 16),          qb.z, acc);
  acc = fmaf(__uint_as_float(u.w & 0xFFFF0000u),  qb.w, acc);
  return acc;
}

// ---------- kernel A: E = bf16(exp(log_trans)) ----------
__global__ void prep_E(const float* __restrict__ lt, unsigned short* __restrict__ E) {
  size_t base = ((size_t)blockIdx.x * 256 + threadIdx.x) * 8;
  float4 a = ((const float4*)(lt + base))[0];
  float4 b = ((const float4*)(lt + base))[1];
  uint4 o;
  o.x = (unsigned)f2bf_rn(__expf(a.x)) | ((unsigned)f2bf_rn(__expf(a.y)) << 16);
  o.y = (unsigned)f2bf_rn(__expf(a.z)) | ((unsigned)f2bf_rn(__expf(a.w)) << 16);
  o.z = (unsigned)f2bf_rn(__expf(b.x)) | ((unsigned)f2bf_rn(__expf(b.y)) << 16);
  o.w = (unsigned)f2bf_rn(__expf(b.z)) | ((unsigned)f2bf_rn(__expf(b.w)) << 16);
  ((uint4*)(E + base))[0] = o;
}

// ---------- kernel B: q0 = exp(log_M0 + log_emit[0]) (positive sign = t=0) ----------
__global__ void init_q(const float* __restrict__ m0, const float* __restrict__ emit,
                       float* __restrict__ q) {
  int i = blockIdx.x * 256 + threadIdx.x;
  q[i] = __expf(m0[i] + emit[i]);
}

// ---------- kernel C: persistent forward recursion ----------
// 256 blocks x 512 threads (8 waves), 1 block/CU (148 KB LDS). Block b owns
// rows [16b,16b+16) (E-slice in LDS, padded pitch). Wave w owns cols
// [512w,512w+512); lane = (row lane&15, colgroup lane>>4 -> 128 cols).
// Sign-parity data-as-flag sync (see R5): writer at step t stores q * s_t,
// s_t = ((t>>1)&1)? -1 : +1; consumers poll data directly.
__global__ void __launch_bounds__(512, 1)
hmm_fwd(const unsigned short* __restrict__ E, const float* __restrict__ emit,
        float* q, float* out) {
  __shared__ unsigned short es[16 * RP];   // 131,328 B
  __shared__ float qs[SS];                 // 16 KiB
  __shared__ float part[8 * 16];
  __shared__ float wsum[8];
  const int b    = blockIdx.x;
  const int tid  = threadIdx.x;
  const int w    = tid >> 6;
  const int lane = tid & 63;
  const int r    = lane & 15;   // row within block's 16
  const int g    = lane >> 4;   // colgroup within wave's 512 cols

  // one-time: global -> LDS copy of block's 16x4096 slice, padded pitch
  {
    const uint4* src = (const uint4*)(E + ((size_t)b << 4) * SS);
#pragma unroll
    for (int i = 0; i < 16; ++i) {
      int idx = tid + (i << 9);        // 0..8191 granules (16B each)
      int row = idx >> 9;              // 0..15
      int gr  = idx & 511;             // granule within row
      ((uint4*)(es + row * RP))[gr] = src[(row << 9) + gr];
    }
  }
  __syncthreads();

  // this lane's E strip (row r, cols 512w+128g .. +128) and q strip
  const uint4* ep  = (const uint4*)(es + r * RP + (w << 9) + (g << 7));
  const v4f*   qp0 = (const v4f*)(qs + (w << 9) + (g << 7));

  for (int t = 1; t <= TT; ++t) {
    // poll q_{t-1} directly (expected stored-sign of step t-1), stage to LDS
    const unsigned e = (unsigned)(((t - 1) >> 1) & 1) << 31;
    {
      const v4f* qsrc4 = (const v4f*)(q + ((t - 1) & 1) * SS);
      v4f va, vb;
      for (;;) {
        llc_load4x2(qsrc4 + tid, va, vb);      // cols 4t..+4 and 2048+4t..+4
        unsigned o = orsgn(va, e) | orsgn(vb, e);
        if (!(o >> 31)) break;
      }
      uint4* qs4 = (uint4*)qs;                 // strip sign exactly via XOR
      qs4[tid]       = xorsgn(va, e);
      qs4[tid + 512] = xorsgn(vb, e);
    }
    __syncthreads();   // (C) stage complete; also orders prev-step part reads

    // early emit load (publisher lanes): HBM/L2 latency overlaps GEMV
    float em = 0.f;
    if (tid < 16) em = emit[(size_t)t * SS + (b << 4) + tid];

    // GEMV strip: 128 cols x 1 row per lane, all from LDS (conflict-free)
    float acc = 0.f;
#pragma unroll
    for (int j = 0; j < 16; ++j)
      acc = dot8(ep[j], qp0[2 * j], qp0[2 * j + 1], acc);

    // combine colgroups (lanes r, r+16, r+32, r+48)
    acc += __shfl_xor(acc, 16);
    acc += __shfl_xor(acc, 32);
    if (lane < 16) part[(w << 4) + lane] = acc;
    __syncthreads();   // (F) all GEMV reads of qs done; partials visible

    // combine waves + emission + publish (one 16-lane dword store)
    if (tid < 16) {
      float s = part[tid]      + part[tid + 16] + part[tid + 32] + part[tid + 48]
              + part[tid + 64] + part[tid + 80] + part[tid + 96] + part[tid + 112];
      float scale = ((t & 255) == 0) ? 0x1p-46f : 1.0f;   // exact pow2 renorm
      if ((t >> 1) & 1) scale = -scale;                    // embed parity sign
      llc_store_drain(q + (t & 1) * SS + (b << 4) + tid, s * (__expf(em) * scale));
    }
  }

  // final reduction: q_T (t=2048) in buffer 0, stored sign positive
  if (b == 0) {
    const v4f* qf4 = (const v4f*)q;
    v4f va, vb;
    for (;;) {
      llc_load4x2(qf4 + tid, va, vb);
      unsigned o = orsgn(va, 0) | orsgn(vb, 0);
      if (!(o >> 31)) break;
    }
    float s = va.x + va.y + va.z + va.w + vb.x + vb.y + vb.z + vb.w;
#pragma unroll
    for (int m = 32; m > 0; m >>= 1) s += __shfl_xor(s, m);
    if (lane == 0) wsum[w] = s;
    __syncthreads();
    if (tid == 0) {
      float tot = wsum[0] + wsum[1] + wsum[2] + wsum[3]
                + wsum[4] + wsum[5] + wsum[6] + wsum[7];
      out[0] = logf(tot) + 368.0f * 0.693147180559945f;   // 8 rescales * 46 * ln2
    }
  }
}

// ---------- launch ----------
extern "C" void kernel_launch(void* const* d_in, const int* in_sizes, int n_in,
                              void* d_out, int out_size, void* d_ws, size_t ws_size,
                              hipStream_t stream) {
  const float* log_M0    = (const float*)d_in[0];
  const float* log_trans = (const float*)d_in[1];
  const float* log_emit  = (const float*)d_in[2];
  // d_in[3] = T (fixed 2048, unused)

  unsigned short* E = (unsigned short*)d_ws;                   // 32 MiB bf16
  float* q  = (float*)((char*)d_ws + (size_t)SS * SS * 2);     // 2 x 16 KiB (0xAA poison = negative)
  float* out = (float*)d_out;

  hipLaunchKernelGGL(prep_E, dim3((SS * SS) / 2048), dim3(256), 0, stream, log_trans, E);
  hipLaunchKernelGGL(init_q, dim3(SS / 256), dim3(256), 0, stream, log_M0, log_emit, q);
  hipLaunchKernelGGL(hmm_fwd, dim3(256), dim3(512), 0, stream, E, log_emit, q, out);
}

// Round 7
// 6905.551 us; speedup vs baseline: 1.0328x; 1.0328x over previous
//
#include <hip/hip_runtime.h>
#include <hip/hip_bf16.h>

#define SS 4096
#define TT 2048
#define RP 4104   // padded LDS E-row pitch (ushorts): 2052 dw, 513≡1 mod 8 → rows spread quads

// clang native vector type: usable directly in asm "v" constraints
typedef float v4f __attribute__((ext_vector_type(4)));

// ---------- LLC-coherent (agent) memory ops, hand-rolled ----------
// sc0 sc1 => bypass non-coherent per-XCD L2, serve at Infinity Cache.

__device__ __forceinline__ void llc_load4x2(const v4f* p, v4f& a, v4f& b) {
  asm volatile(
      "global_load_dwordx4 %0, %2, off sc0 sc1\n\t"
      "global_load_dwordx4 %1, %3, off sc0 sc1\n\t"
      "s_waitcnt vmcnt(0)"
      : "=&v"(a), "=&v"(b)
      : "v"(p), "v"(p + 512)
      : "memory");
}

__device__ __forceinline__ void llc_store_drain(float* p, float v) {
  asm volatile("global_store_dword %0, %1, off sc0 sc1\n\t"
               "s_waitcnt vmcnt(0)"
               :: "v"(p), "v"(v) : "memory");
}

// ---------- helpers ----------

__device__ __forceinline__ unsigned short f2bf_rn(float f) {
  unsigned int u = __float_as_uint(f);
  u += 0x7FFFu + ((u >> 16) & 1u);   // RNE; inputs positive finite
  return (unsigned short)(u >> 16);
}

// OR of (sign-adjusted) words: ready iff top bit of result is 0
__device__ __forceinline__ unsigned orsgn(v4f v, unsigned e) {
  return (__float_as_uint(v.x) ^ e) | (__float_as_uint(v.y) ^ e)
       | (__float_as_uint(v.z) ^ e) | (__float_as_uint(v.w) ^ e);
}

__device__ __forceinline__ uint4 xorsgn(v4f v, unsigned e) {
  uint4 r;
  r.x = __float_as_uint(v.x) ^ e;  r.y = __float_as_uint(v.y) ^ e;
  r.z = __float_as_uint(v.z) ^ e;  r.w = __float_as_uint(v.w) ^ e;
  return r;
}

__device__ __forceinline__ float dot8(uint4 u, v4f qa, v4f qb, float acc) {
  acc = fmaf(__uint_as_float(u.x << 16),          qa.x, acc);
  acc = fmaf(__uint_as_float(u.x & 0xFFFF0000u),  qa.y, acc);
  acc = fmaf(__uint_as_float(u.y << 16),          qa.z, acc);
  acc = fmaf(__uint_as_float(u.y & 0xFFFF0000u),  qa.w, acc);
  acc = fmaf(__uint_as_float(u.z << 16),          qb.x, acc);
  acc = fmaf(__uint_as_float(u.z & 0xFFFF0000u),  qb.y, acc);
  acc = fmaf(__uint_as_float(u.w << 16),          qb.z, acc);
  acc = fmaf(__uint_as_float(u.w & 0xFFFF0000u),  qb.w, acc);
  return acc;
}

// ---------- kernel A: E = bf16(exp(log_trans)) ----------
__global__ void prep_E(const float* __restrict__ lt, unsigned short* __restrict__ E) {
  size_t base = ((size_t)blockIdx.x * 256 + threadIdx.x) * 8;
  float4 a = ((const float4*)(lt + base))[0];
  float4 b = ((const float4*)(lt + base))[1];
  uint4 o;
  o.x = (unsigned)f2bf_rn(__expf(a.x)) | ((unsigned)f2bf_rn(__expf(a.y)) << 16);
  o.y = (unsigned)f2bf_rn(__expf(a.z)) | ((unsigned)f2bf_rn(__expf(a.w)) << 16);
  o.z = (unsigned)f2bf_rn(__expf(b.x)) | ((unsigned)f2bf_rn(__expf(b.y)) << 16);
  o.w = (unsigned)f2bf_rn(__expf(b.z)) | ((unsigned)f2bf_rn(__expf(b.w)) << 16);
  ((uint4*)(E + base))[0] = o;
}

// ---------- kernel B: q0 = exp(log_M0 + log_emit[0]) (positive sign = t=0) ----------
__global__ void init_q(const float* __restrict__ m0, const float* __restrict__ emit,
                       float* __restrict__ q) {
  int i = blockIdx.x * 256 + threadIdx.x;
  q[i] = __expf(m0[i] + emit[i]);
}

// ---------- kernel C: persistent forward recursion ----------
// 256 blocks x 512 threads (8 waves), 1 block/CU. Block b owns rows
// [16b,16b+16) (E-slice in LDS, padded pitch). Wave w owns cols
// [512w,512w+512); lane = (row lane&15, colgroup lane>>4 -> 128 cols).
// Staged q is padded 1 uint4-granule per 128-float group so the 4 colgroups
// of a wave read 4 distinct bank-quads (16-lane broadcast each, 1 cy).
// Sign-parity data-as-flag sync (R5): writer at step t stores q * s_t,
// s_t = ((t>>1)&1)? -1 : +1; consumers poll data directly.
__global__ void __launch_bounds__(512, 1)
hmm_fwd(const unsigned short* __restrict__ E, const float* __restrict__ emit,
        float* q, float* out) {
  __shared__ unsigned short es[16 * RP];   // 131,328 B
  __shared__ float qs[SS + (SS >> 5)];     // 4224 floats = 16.5 KiB (group-padded)
  __shared__ float part[8 * 16];
  __shared__ float wsum[8];
  const int b    = blockIdx.x;
  const int tid  = threadIdx.x;
  const int w    = tid >> 6;
  const int lane = tid & 63;
  const int r    = lane & 15;   // row within block's 16
  const int g    = lane >> 4;   // colgroup within wave's 512 cols

  // one-time: global -> LDS copy of block's 16x4096 slice, padded pitch
  {
    const uint4* src = (const uint4*)(E + ((size_t)b << 4) * SS);
#pragma unroll
    for (int i = 0; i < 16; ++i) {
      int idx = tid + (i << 9);        // 0..8191 granules (16B each)
      int row = idx >> 9;              // 0..15
      int gr  = idx & 511;             // granule within row
      ((uint4*)(es + row * RP))[gr] = src[(row << 9) + gr];
    }
  }
  __syncthreads();

  // this lane's E strip (row r, cols 512w+128g..+128) and padded q strip
  const uint4* ep  = (const uint4*)(es + r * RP + (w << 9) + (g << 7));
  const v4f*   qp0 = (const v4f*)qs + 33 * ((w << 2) + g);   // 132-dw group pitch

  for (int t = 1; t <= TT; ++t) {
    // poll q_{t-1} directly (expected stored-sign of step t-1), stage to LDS
    const unsigned e = (unsigned)(((t - 1) >> 1) & 1) << 31;
    {
      const v4f* qsrc4 = (const v4f*)(q + ((t - 1) & 1) * SS);
      v4f va, vb;
      for (;;) {
        llc_load4x2(qsrc4 + tid, va, vb);      // granules tid and tid+512
        unsigned o = orsgn(va, e) | orsgn(vb, e);
        if (!(o >> 31)) break;
      }
      uint4* qs4 = (uint4*)qs;                 // strip sign exactly via XOR
      int p1 = tid;        p1 += (p1 >> 5);    // padded granule index
      int p2 = tid + 512;  p2 += (p2 >> 5);
      qs4[p1] = xorsgn(va, e);
      qs4[p2] = xorsgn(vb, e);
    }
    __syncthreads();   // stage complete; also orders prev-step part reads

    // early emit load (publisher lanes): HBM/L2 latency overlaps GEMV
    float em = 0.f;
    if (tid < 16) em = emit[(size_t)t * SS + (b << 4) + tid];

    // GEMV strip: 128 cols x 1 row per lane, all from LDS
    float acc = 0.f;
#pragma unroll
    for (int j = 0; j < 16; ++j)
      acc = dot8(ep[j], qp0[2 * j], qp0[2 * j + 1], acc);

    // combine colgroups (lanes r, r+16, r+32, r+48)
    acc += __shfl_xor(acc, 16);
    acc += __shfl_xor(acc, 32);
    if (lane < 16) part[(w << 4) + lane] = acc;
    __syncthreads();   // all GEMV reads of qs done; partials visible

    // combine waves + emission + publish (one 16-lane dword store)
    if (tid < 16) {
      float s = part[tid]      + part[tid + 16] + part[tid + 32] + part[tid + 48]
              + part[tid + 64] + part[tid + 80] + part[tid + 96] + part[tid + 112];
      float scale = ((t & 255) == 0) ? 0x1p-46f : 1.0f;   // exact pow2 renorm
      if ((t >> 1) & 1) scale = -scale;                    // embed parity sign
      llc_store_drain(q + (t & 1) * SS + (b << 4) + tid, s * (__expf(em) * scale));
    }
  }

  // final reduction: q_T (t=2048) in buffer 0, stored sign positive
  if (b == 0) {
    const v4f* qf4 = (const v4f*)q;
    v4f va, vb;
    for (;;) {
      llc_load4x2(qf4 + tid, va, vb);
      unsigned o = orsgn(va, 0) | orsgn(vb, 0);
      if (!(o >> 31)) break;
    }
    float s = va.x + va.y + va.z + va.w + vb.x + vb.y + vb.z + vb.w;
#pragma unroll
    for (int m = 32; m > 0; m >>= 1) s += __shfl_xor(s, m);
    if (lane == 0) wsum[w] = s;
    __syncthreads();
    if (tid == 0) {
      float tot = wsum[0] + wsum[1] + wsum[2] + wsum[3]
                + wsum[4] + wsum[5] + wsum[6] + wsum[7];
      out[0] = logf(tot) + 368.0f * 0.693147180559945f;   // 8 rescales * 46 * ln2
    }
  }
}

// ---------- launch ----------
extern "C" void kernel_launch(void* const* d_in, const int* in_sizes, int n_in,
                              void* d_out, int out_size, void* d_ws, size_t ws_size,
                              hipStream_t stream) {
  const float* log_M0    = (const float*)d_in[0];
  const float* log_trans = (const float*)d_in[1];
  const float* log_emit  = (const float*)d_in[2];
  // d_in[3] = T (fixed 2048, unused)

  unsigned short* E = (unsigned short*)d_ws;                   // 32 MiB bf16
  float* q  = (float*)((char*)d_ws + (size_t)SS * SS * 2);     // 2 x 16 KiB (0xAA poison = negative)
  float* out = (float*)d_out;

  hipLaunchKernelGGL(prep_E, dim3((SS * SS) / 2048), dim3(256), 0, stream, log_trans, E);
  hipLaunchKernelGGL(init_q, dim3(SS / 256), dim3(256), 0, stream, log_M0, log_emit, q);
  hipLaunchKernelGGL(hmm_fwd, dim3(256), dim3(512), 0, stream, E, log_emit, q, out);
}

// Round 8
// 6381.078 us; speedup vs baseline: 1.1176x; 1.0822x over previous
//
#include <hip/hip_runtime.h>
#include <hip/hip_bf16.h>

#define SS 4096
#define TT 2048

// clang native vector type: usable directly in asm "v" constraints
typedef float v4f __attribute__((ext_vector_type(4)));

// ---------- LLC-coherent (agent) memory ops, hand-rolled ----------
// sc0 sc1 => bypass non-coherent per-XCD L2, serve at Infinity Cache.

__device__ __forceinline__ void llc_load4x4(const v4f* p,
                                            v4f& a, v4f& b, v4f& c, v4f& d) {
  asm volatile(
      "global_load_dwordx4 %0, %4, off sc0 sc1\n\t"
      "global_load_dwordx4 %1, %5, off sc0 sc1\n\t"
      "global_load_dwordx4 %2, %6, off sc0 sc1\n\t"
      "global_load_dwordx4 %3, %7, off sc0 sc1\n\t"
      "s_waitcnt vmcnt(0)"
      : "=&v"(a), "=&v"(b), "=&v"(c), "=&v"(d)
      : "v"(p), "v"(p + 256), "v"(p + 512), "v"(p + 768)
      : "memory");
}

__device__ __forceinline__ void llc_store_drain(float* p, float v) {
  asm volatile("global_store_dword %0, %1, off sc0 sc1\n\t"
               "s_waitcnt vmcnt(0)"
               :: "v"(p), "v"(v) : "memory");
}

// ---------- helpers ----------

// OR of (sign-adjusted) words: ready iff top bit of result is 0
__device__ __forceinline__ unsigned orsgn(v4f v, unsigned e) {
  return (__float_as_uint(v.x) ^ e) | (__float_as_uint(v.y) ^ e)
       | (__float_as_uint(v.z) ^ e) | (__float_as_uint(v.w) ^ e);
}

__device__ __forceinline__ uint4 xorsgn(v4f v, unsigned e) {
  uint4 r;
  r.x = __float_as_uint(v.x) ^ e;  r.y = __float_as_uint(v.y) ^ e;
  r.z = __float_as_uint(v.z) ^ e;  r.w = __float_as_uint(v.w) ^ e;
  return r;
}

// ---------- kernel B: q0 = exp(log_M0 + log_emit[0]) (positive sign = t=0) ----------
__global__ void init_q(const float* __restrict__ m0, const float* __restrict__ emit,
                       float* __restrict__ q) {
  int i = blockIdx.x * 256 + threadIdx.x;
  q[i] = __expf(m0[i] + emit[i]);
}

// ---------- kernel C: persistent forward recursion, E in VGPRs ----------
// 256 blocks x 256 threads (4 waves), 1 block/CU. Block b owns rows
// [16b,16b+16); wave w owns rows 4w..4w+3 (within block). Lane = (row
// lane&3, colgroup s=lane>>2); lane's E strip = row x cols
// [128s,128s+128) U [2048+128s,+128) held in 256 fp32 VGPRs (loaded once
// from exp(log_trans) -- no LDS E, no bf16 loss). q staged to LDS in
// 33-granule padded groups: reads = 16 addrs over 8 bank-quads = 2-way
// (free). Wave-local publish (no block barrier on the publish path).
// Sign-parity data-as-flag sync (R5): writer at step t stores q * s_t,
// s_t = ((t>>1)&1)? -1 : +1; consumers poll the data directly.
__global__ void __launch_bounds__(256, 1)
hmm_fwd(const float* __restrict__ lt, const float* __restrict__ emit,
        float* q, float* out) {
  __shared__ float qs[4224];   // 1056 granules: 32 groups x 33 (pad granule each)
  __shared__ float wsum[4];
  const int b    = blockIdx.x;
  const int tid  = threadIdx.x;
  const int w    = tid >> 6;
  const int lane = tid & 63;
  const int r    = lane & 3;    // row within wave's 4
  const int s    = lane >> 2;   // colgroup 0..15
  const int grow = (b << 4) + (w << 2) + r;   // global row

  // one-time: E strip -> 256 VGPRs (f32, exact exp of log_trans)
  float eR[256];
  {
    const float* rowp = lt + (size_t)grow * SS;
#pragma unroll
    for (int st = 0; st < 2; ++st)
#pragma unroll
      for (int k = 0; k < 32; ++k) {
        v4f v = *(const v4f*)(rowp + 128 * (s + 16 * st) + 4 * k);
        int j = (st * 32 + k) * 4;
        eR[j + 0] = __expf(v.x);
        eR[j + 1] = __expf(v.y);
        eR[j + 2] = __expf(v.z);
        eR[j + 3] = __expf(v.w);
      }
  }

  const int pbase = tid + (tid >> 5);          // padded granule for staging
  const v4f* qA = (const v4f*)qs + 33 * s;     // group s
  const v4f* qB = qA + 33 * 16;                // group s+16

  for (int t = 1; t <= TT; ++t) {
    // poll q_{t-1} directly (expected stored-sign of step t-1), stage to LDS
    const unsigned e = (unsigned)(((t - 1) >> 1) & 1) << 31;
    {
      const v4f* qsrc4 = (const v4f*)(q + ((t - 1) & 1) * SS);
      v4f va, vb, vc, vd;
      for (;;) {
        llc_load4x4(qsrc4 + tid, va, vb, vc, vd);
        unsigned o = orsgn(va, e) | orsgn(vb, e) | orsgn(vc, e) | orsgn(vd, e);
        if (!(o >> 31)) break;
      }
      uint4* qs4 = (uint4*)qs;                 // strip sign exactly via XOR
      qs4[pbase]       = xorsgn(va, e);
      qs4[pbase + 264] = xorsgn(vb, e);
      qs4[pbase + 528] = xorsgn(vc, e);
      qs4[pbase + 792] = xorsgn(vd, e);
    }
    __syncthreads();

    // emit for this lane's row (16-lane broadcast; issued early, used late)
    float em = emit[(size_t)t * SS + grow];

    // GEMV strip: 256 cols, E from VGPRs, q from LDS (2-way = free)
    float a0 = 0.f, a1 = 0.f, a2 = 0.f, a3 = 0.f;
#pragma unroll
    for (int k = 0; k < 32; ++k) {
      v4f qa = qA[k], qb = qB[k];
      a0 = fmaf(eR[4 * k + 0], qa.x, a0);
      a1 = fmaf(eR[4 * k + 1], qa.y, a1);
      a2 = fmaf(eR[4 * k + 2], qa.z, a2);
      a3 = fmaf(eR[4 * k + 3], qa.w, a3);
      a0 = fmaf(eR[128 + 4 * k + 0], qb.x, a0);
      a1 = fmaf(eR[128 + 4 * k + 1], qb.y, a1);
      a2 = fmaf(eR[128 + 4 * k + 2], qb.z, a2);
      a3 = fmaf(eR[128 + 4 * k + 3], qb.w, a3);
    }
    float acc = (a0 + a1) + (a2 + a3);

    // reduce over the 16 colgroups (all 4 rows simultaneously)
    acc += __shfl_xor(acc, 4);
    acc += __shfl_xor(acc, 8);
    acc += __shfl_xor(acc, 16);
    acc += __shfl_xor(acc, 32);

    // wave-local publish: lanes 0..3 hold rows 4w..4w+3 -> one coalesced store
    if (lane < 4) {
      float scale = ((t & 255) == 0) ? 0x1p-46f : 1.0f;   // exact pow2 renorm
      if ((t >> 1) & 1) scale = -scale;                    // embed parity sign
      llc_store_drain(q + (t & 1) * SS + grow, acc * (__expf(em) * scale));
    }
    __syncthreads();   // qs stable until all waves finished their GEMV reads
  }

  // final reduction: q_T (t=2048) in buffer 0, stored sign positive
  if (b == 0) {
    const v4f* qf4 = (const v4f*)q;
    v4f va, vb, vc, vd;
    for (;;) {
      llc_load4x4(qf4 + tid, va, vb, vc, vd);
      unsigned o = orsgn(va, 0) | orsgn(vb, 0) | orsgn(vc, 0) | orsgn(vd, 0);
      if (!(o >> 31)) break;
    }
    float sm = va.x + va.y + va.z + va.w + vb.x + vb.y + vb.z + vb.w
             + vc.x + vc.y + vc.z + vc.w + vd.x + vd.y + vd.z + vd.w;
#pragma unroll
    for (int m = 32; m > 0; m >>= 1) sm += __shfl_xor(sm, m);
    if (lane == 0) wsum[w] = sm;
    __syncthreads();
    if (tid == 0) {
      float tot = wsum[0] + wsum[1] + wsum[2] + wsum[3];
      out[0] = logf(tot) + 368.0f * 0.693147180559945f;   // 8 rescales * 46 * ln2
    }
  }
}

// ---------- launch ----------
extern "C" void kernel_launch(void* const* d_in, const int* in_sizes, int n_in,
                              void* d_out, int out_size, void* d_ws, size_t ws_size,
                              hipStream_t stream) {
  const float* log_M0    = (const float*)d_in[0];
  const float* log_trans = (const float*)d_in[1];
  const float* log_emit  = (const float*)d_in[2];
  // d_in[3] = T (fixed 2048, unused)

  float* q   = (float*)d_ws;    // 2 x 16 KiB double buffer (0xAA poison = negative)
  float* out = (float*)d_out;

  hipLaunchKernelGGL(init_q, dim3(SS / 256), dim3(256), 0, stream, log_M0, log_emit, q);
  hipLaunchKernelGGL(hmm_fwd, dim3(256), dim3(256), 0, stream, log_trans, log_emit, q, out);
}

// Round 9
// 5694.547 us; speedup vs baseline: 1.2524x; 1.1206x over previous
//
#include <hip/hip_runtime.h>
#include <hip/hip_bf16.h>

#define SS 4096
#define TT 2048

// clang native vector type: usable directly in asm "v" constraints
typedef float v4f __attribute__((ext_vector_type(4)));

// ---------- LLC-coherent (agent) memory ops, hand-rolled ----------
// sc0 sc1 => bypass non-coherent per-XCD L2, serve at Infinity Cache.

// issue 4 LLC loads, NO wait (in-flight batch)
__device__ __forceinline__ void llc_issue4(const v4f* p,
                                           v4f& a, v4f& b, v4f& c, v4f& d) {
  asm volatile(
      "global_load_dwordx4 %0, %4, off sc0 sc1\n\t"
      "global_load_dwordx4 %1, %5, off sc0 sc1\n\t"
      "global_load_dwordx4 %2, %6, off sc0 sc1\n\t"
      "global_load_dwordx4 %3, %7, off sc0 sc1"
      : "=&v"(a), "=&v"(b), "=&v"(c), "=&v"(d)
      : "v"(p), "v"(p + 256), "v"(p + 512), "v"(p + 768)
      : "memory");
}

// wait until <=4 vmem outstanding (i.e. the OLDER batch has landed);
// ties the batch through the asm so the values are only read post-wait
__device__ __forceinline__ void llc_wait4(v4f& a, v4f& b, v4f& c, v4f& d) {
  asm volatile("s_waitcnt vmcnt(4)"
               : "+v"(a), "+v"(b), "+v"(c), "+v"(d) :: "memory");
}

// full drain; ties BOTH batches so stale in-flight loads can't land in
// registers the compiler has re-used
__device__ __forceinline__ void llc_drain8(v4f& a0, v4f& a1, v4f& a2, v4f& a3,
                                           v4f& b0, v4f& b1, v4f& b2, v4f& b3) {
  asm volatile("s_waitcnt vmcnt(0)"
               : "+v"(a0), "+v"(a1), "+v"(a2), "+v"(a3),
                 "+v"(b0), "+v"(b1), "+v"(b2), "+v"(b3) :: "memory");
}

__device__ __forceinline__ void llc_store4_drain(v4f* p, v4f v) {
  asm volatile("global_store_dwordx4 %0, %1, off sc0 sc1\n\t"
               "s_waitcnt vmcnt(0)"
               :: "v"(p), "v"(v) : "memory");
}

// ---------- helpers ----------

__device__ __forceinline__ unsigned short f2bf_rn(float f) {
  unsigned int u = __float_as_uint(f);
  u += 0x7FFFu + ((u >> 16) & 1u);   // RNE; inputs positive finite
  return (unsigned short)(u >> 16);
}

// OR of (sign-adjusted) words: ready iff top bit of result is 0
__device__ __forceinline__ unsigned orsgn(v4f v, unsigned e) {
  return (__float_as_uint(v.x) ^ e) | (__float_as_uint(v.y) ^ e)
       | (__float_as_uint(v.z) ^ e) | (__float_as_uint(v.w) ^ e);
}

__device__ __forceinline__ uint4 xorsgn(v4f v, unsigned e) {
  uint4 r;
  r.x = __float_as_uint(v.x) ^ e;  r.y = __float_as_uint(v.y) ^ e;
  r.z = __float_as_uint(v.z) ^ e;  r.w = __float_as_uint(v.w) ^ e;
  return r;
}

__device__ __forceinline__ float dot8(uint4 u, v4f qa, v4f qb, float acc) {
  acc = fmaf(__uint_as_float(u.x << 16),          qa.x, acc);
  acc = fmaf(__uint_as_float(u.x & 0xFFFF0000u),  qa.y, acc);
  acc = fmaf(__uint_as_float(u.y << 16),          qa.z, acc);
  acc = fmaf(__uint_as_float(u.y & 0xFFFF0000u),  qa.w, acc);
  acc = fmaf(__uint_as_float(u.z << 16),          qb.x, acc);
  acc = fmaf(__uint_as_float(u.z & 0xFFFF0000u),  qb.y, acc);
  acc = fmaf(__uint_as_float(u.w << 16),          qb.z, acc);
  acc = fmaf(__uint_as_float(u.w & 0xFFFF0000u),  qb.w, acc);
  return acc;
}

// padded stage: float-granule g -> LDS granule g + (g>>1) (pairs stay adjacent)
__device__ __forceinline__ void stage_q(float* qs, int tid, unsigned e,
                                        v4f va, v4f vb, v4f vc, v4f vd) {
  uint4* qs4 = (uint4*)qs;
  int p0 = tid + (tid >> 1);
  qs4[p0]        = xorsgn(va, e);
  qs4[p0 + 384]  = xorsgn(vb, e);   // g=tid+256
  qs4[p0 + 768]  = xorsgn(vc, e);   // g=tid+512
  qs4[p0 + 1152] = xorsgn(vd, e);   // g=tid+768
}

// ---------- kernel A: E = bf16(exp(log_trans)) ----------
__global__ void prep_E(const float* __restrict__ lt, unsigned short* __restrict__ E) {
  size_t base = ((size_t)blockIdx.x * 256 + threadIdx.x) * 8;
  float4 a = ((const float4*)(lt + base))[0];
  float4 b = ((const float4*)(lt + base))[1];
  uint4 o;
  o.x = (unsigned)f2bf_rn(__expf(a.x)) | ((unsigned)f2bf_rn(__expf(a.y)) << 16);
  o.y = (unsigned)f2bf_rn(__expf(a.z)) | ((unsigned)f2bf_rn(__expf(a.w)) << 16);
  o.z = (unsigned)f2bf_rn(__expf(b.x)) | ((unsigned)f2bf_rn(__expf(b.y)) << 16);
  o.w = (unsigned)f2bf_rn(__expf(b.z)) | ((unsigned)f2bf_rn(__expf(b.w)) << 16);
  ((uint4*)(E + base))[0] = o;
}

// ---------- kernel B: q0 = exp(log_M0 + log_emit[0]) (positive sign = t=0) ----------
__global__ void init_q(const float* __restrict__ m0, const float* __restrict__ emit,
                       float* __restrict__ q) {
  int i = blockIdx.x * 256 + threadIdx.x;
  q[i] = __expf(m0[i] + emit[i]);
}

// ---------- kernel C: persistent forward recursion (R5 structure, tightened) ----------
// 256 blocks x 256 threads (4 waves), 1 block/CU. Block b owns rows
// [16b,16b+16) (E bf16 slice in LDS); wave w rows 4w..4w+3, wave-local
// publish. Sign-parity data-as-flag sync (writer at step t stores q*s_t,
// s_t = ((t>>1)&1)? -1:+1; poison 0xAA is negative). Tightenings vs R5:
// ping-pong poll (vmcnt(4) alternation halves detect period), emit
// prefetched one step ahead, ONE barrier/step (poll success for t+1 proves
// all waves finished GEMV-t reads), padded q staging (all 8 bank-quads).
__global__ void __launch_bounds__(256, 1)
hmm_fwd(const unsigned short* __restrict__ E, const float* __restrict__ emit,
        float* q, float* out) {
  __shared__ unsigned short es[16 * SS];   // 128 KiB
  __shared__ float qs[6144];               // 24 KiB (padded: 1536 granules)
  __shared__ float wsum[4];
  const int b    = blockIdx.x;
  const int tid  = threadIdx.x;
  const int w    = tid >> 6;
  const int lane = tid & 63;
  const int row0 = (b << 4) + (w << 2);

  // one-time: global -> LDS copy of this block's 16x4096 bf16 slice
  {
    const uint4* src = (const uint4*)(E + ((size_t)b << 4) * SS);
    uint4* dst = (uint4*)es;
#pragma unroll
    for (int i = 0; i < 32; ++i)
      dst[tid + (i << 8)] = src[tid + (i << 8)];
  }
  __syncthreads();

  const uint4* ev = (const uint4*)es;
  const uint4* e0 = ev + (size_t)((w << 2) + 0) * 512;
  const uint4* e1 = ev + (size_t)((w << 2) + 1) * 512;
  const uint4* e2 = ev + (size_t)((w << 2) + 2) * 512;
  const uint4* e3 = ev + (size_t)((w << 2) + 3) * 512;

  // emit for step 1, prefetched before the loop (lane 0 per wave)
  v4f em = {0.f, 0.f, 0.f, 0.f};
  if (lane == 0) em = *(const v4f*)(emit + (size_t)1 * SS + row0);

  for (int t = 1; t <= TT; ++t) {
    const unsigned e = (unsigned)(((t - 1) >> 1) & 1) << 31;
    // ping-pong poll of q_{t-1}: two 16-float batches in flight, alternate
    {
      const v4f* p = (const v4f*)(q + ((t - 1) & 1) * SS) + tid;
      v4f a0, a1, a2, a3, b0, b1, b2, b3;
      llc_issue4(p, a0, a1, a2, a3);
      for (;;) {
        llc_issue4(p, b0, b1, b2, b3);
        llc_wait4(a0, a1, a2, a3);
        if (!((orsgn(a0, e) | orsgn(a1, e) | orsgn(a2, e) | orsgn(a3, e)) >> 31)) {
          stage_q(qs, tid, e, a0, a1, a2, a3);
          break;
        }
        llc_issue4(p, a0, a1, a2, a3);
        llc_wait4(b0, b1, b2, b3);
        if (!((orsgn(b0, e) | orsgn(b1, e) | orsgn(b2, e) | orsgn(b3, e)) >> 31)) {
          stage_q(qs, tid, e, b0, b1, b2, b3);
          break;
        }
      }
      llc_drain8(a0, a1, a2, a3, b0, b1, b2, b3);  // stale batch lands safely
    }
    __syncthreads();   // the ONLY barrier per step: all staging visible

    // GEMV from LDS: 4 rows per wave, 8 cols x 8 chunks per lane (padded q)
    float acc0 = 0.f, acc1 = 0.f, acc2 = 0.f, acc3 = 0.f;
#pragma unroll
    for (int k = 0; k < 8; ++k) {
      int vi = (k << 6) + lane;
      const v4f* qpair = (const v4f*)(qs + 768 * k + 12 * lane);
      v4f qa = qpair[0], qb = qpair[1];
      acc0 = dot8(e0[vi], qa, qb, acc0);
      acc1 = dot8(e1[vi], qa, qb, acc1);
      acc2 = dot8(e2[vi], qa, qb, acc2);
      acc3 = dot8(e3[vi], qa, qb, acc3);
    }
#pragma unroll
    for (int m = 32; m > 0; m >>= 1) {
      acc0 += __shfl_xor(acc0, m);
      acc1 += __shfl_xor(acc1, m);
      acc2 += __shfl_xor(acc2, m);
      acc3 += __shfl_xor(acc3, m);
    }

    // wave-local publish, then prefetch next step's emit (off critical path)
    float* qdst = q + (t & 1) * SS;
    if (lane == 0) {
      float scale = ((t & 255) == 0) ? 0x1p-46f : 1.0f;   // exact pow2 renorm
      if ((t >> 1) & 1) scale = -scale;                    // embed parity sign
      v4f r;
      r.x = acc0 * (__expf(em.x) * scale);
      r.y = acc1 * (__expf(em.y) * scale);
      r.z = acc2 * (__expf(em.z) * scale);
      r.w = acc3 * (__expf(em.w) * scale);
      llc_store4_drain((v4f*)(qdst + row0), r);
      int tn = (t < TT) ? t + 1 : t;                       // avoid OOB at t=TT
      em = *(const v4f*)(emit + (size_t)tn * SS + row0);   // prefetch em(t+1)
    }
    // no second barrier: poll success for t+1 requires ALL wave-publishes of
    // step t, which implies every wave finished its GEMV-t reads of qs.
  }

  // final reduction: q_T (t=2048) in buffer 0, stored sign positive
  if (b == 0) {
    const v4f* qf4 = (const v4f*)q + tid;
    v4f va, vb, vc, vd;
    for (;;) {
      llc_issue4(qf4, va, vb, vc, vd);
      asm volatile("s_waitcnt vmcnt(0)"
                   : "+v"(va), "+v"(vb), "+v"(vc), "+v"(vd) :: "memory");
      if (!((orsgn(va, 0) | orsgn(vb, 0) | orsgn(vc, 0) | orsgn(vd, 0)) >> 31))
        break;
    }
    float s = va.x + va.y + va.z + va.w + vb.x + vb.y + vb.z + vb.w
            + vc.x + vc.y + vc.z + vc.w + vd.x + vd.y + vd.z + vd.w;
#pragma unroll
    for (int m = 32; m > 0; m >>= 1) s += __shfl_xor(s, m);
    if (lane == 0) wsum[w] = s;
    __syncthreads();
    if (tid == 0) {
      float tot = wsum[0] + wsum[1] + wsum[2] + wsum[3];
      out[0] = logf(tot) + 368.0f * 0.693147180559945f;   // 8 rescales * 46 * ln2
    }
  }
}

// ---------- launch ----------
extern "C" void kernel_launch(void* const* d_in, const int* in_sizes, int n_in,
                              void* d_out, int out_size, void* d_ws, size_t ws_size,
                              hipStream_t stream) {
  const float* log_M0    = (const float*)d_in[0];
  const float* log_trans = (const float*)d_in[1];
  const float* log_emit  = (const float*)d_in[2];
  // d_in[3] = T (fixed 2048, unused)

  unsigned short* E = (unsigned short*)d_ws;                   // 32 MiB bf16
  float* q  = (float*)((char*)d_ws + (size_t)SS * SS * 2);     // 2 x 16 KiB (0xAA poison = negative)
  float* out = (float*)d_out;

  hipLaunchKernelGGL(prep_E, dim3((SS * SS) / 2048), dim3(256), 0, stream, log_trans, E);
  hipLaunchKernelGGL(init_q, dim3(SS / 256), dim3(256), 0, stream, log_M0, log_emit, q);
  hipLaunchKernelGGL(hmm_fwd, dim3(256), dim3(256), 0, stream, E, log_emit, q, out);
}